// Round 2
// baseline (445.272 us; speedup 1.0000x reference)
//
#include <hip/hip_runtime.h>

// D8 fused GELU: isotypic->regular butterfly, gelu, regular->isotypic butterfly.
// B=16, N=1024, C=512. All fp32. Memory-bound: 256MB in + 256MB out.

#define SQ24 0.3535533906f

__device__ __forceinline__ float gelu_f(float x) {
    // gelu(x) ~= x * sigmoid(1.5957691216*x*(1+0.044715*x^2))  (tanh approx)
    float x2 = x * x;
    float z  = 1.5957691216057308f * x * fmaf(0.044715f, x2, 1.0f);
    // clamp so __expf never overflows to inf (avoids inf/inf NaN path)
    float e  = __expf(fminf(-z, 80.0f));
    return x / (1.0f + e);
}

__device__ __forceinline__ void d8_pointwise(
    float x0, float x1, float x2, float x3,
    float y0, float y1, float y2, float y3,
    float& o0, float& o1, float& o2, float& o3,
    float& o4, float& o5, float& o6, float& o7)
{
    // isotypic_to_regular
    float a = x0 + x1, b = x0 - x1, c = x2 + x3, d = x2 - x3;
    float e = y0 + y1, f = y0 - y1, g = y2 + y3, h = y2 - y3;
    float apc = a + c, amc = a - c, bpd = b + d, bmd = b - d;
    float eph = e + h, emh = e - h, fpg = f + g, fmg = f - g;
    float r0 = SQ24 * (apc + eph);
    float r1 = SQ24 * (amc + fmg);
    float r2 = SQ24 * (apc - eph);
    float r3 = SQ24 * (amc - fmg);
    float r4 = SQ24 * (bpd - fpg);
    float r5 = SQ24 * (bmd - emh);
    float r6 = SQ24 * (bpd + fpg);
    float r7 = SQ24 * (bmd + emh);

    // gelu
    float g0 = gelu_f(r0), g1 = gelu_f(r1), g2 = gelu_f(r2), g3 = gelu_f(r3);
    float g4 = gelu_f(r4), g5 = gelu_f(r5), g6 = gelu_f(r6), g7 = gelu_f(r7);

    // regular_to_isotypic
    float a2 = g0 + g1, b2 = g0 - g1, c2 = g2 + g3, d2 = g2 - g3;
    float e2 = g4 + g5, f2 = g4 - g5, gg = g6 + g7, h2 = g6 - g7;
    float apc2 = a2 + c2, cma = c2 - a2, bpd2 = b2 + d2, bmd2 = b2 - d2;
    float epg = e2 + gg, gme = gg - e2, fph = f2 + h2, fmh = f2 - h2;
    o0 = SQ24 * (apc2 + epg);
    o1 = SQ24 * (apc2 - epg);
    o2 = SQ24 * (bpd2 + fph);
    o3 = SQ24 * (bpd2 - fph);
    o4 = SQ24 * (gme - cma);
    o5 = SQ24 * (bmd2 + fmh);
    o6 = SQ24 * (bmd2 - fmh);
    o7 = SQ24 * (gme + cma);
}

__global__ __launch_bounds__(256) void d8_gelu_kernel(
    const float4* __restrict__ xA1, const float4* __restrict__ xA2,
    const float4* __restrict__ xB1, const float4* __restrict__ xB2,
    const float4* __restrict__ x2d, float4* __restrict__ out, int n4)
{
    const int C4 = 128;              // 512 channels / 4 per float4
    int t = blockIdx.x * blockDim.x + threadIdx.x;
    if (t >= n4) return;

    int bn = t >> 7;                 // which (b,n) row
    int c4 = t & (C4 - 1);
    size_t b2d = (size_t)bn * (4 * C4) + c4;   // x_2d is (BN, 4*C) flat

    float4 a0 = xA1[t], a1 = xA2[t], a2 = xB1[t], a3 = xB2[t];
    float4 b0 = x2d[b2d];
    float4 b1 = x2d[b2d + C4];
    float4 b2 = x2d[b2d + 2 * C4];
    float4 b3 = x2d[b2d + 3 * C4];

    float4 o0, o1, o2, o3, o4, o5, o6, o7;
    d8_pointwise(a0.x, a1.x, a2.x, a3.x, b0.x, b1.x, b2.x, b3.x,
                 o0.x, o1.x, o2.x, o3.x, o4.x, o5.x, o6.x, o7.x);
    d8_pointwise(a0.y, a1.y, a2.y, a3.y, b0.y, b1.y, b2.y, b3.y,
                 o0.y, o1.y, o2.y, o3.y, o4.y, o5.y, o6.y, o7.y);
    d8_pointwise(a0.z, a1.z, a2.z, a3.z, b0.z, b1.z, b2.z, b3.z,
                 o0.z, o1.z, o2.z, o3.z, o4.z, o5.z, o6.z, o7.z);
    d8_pointwise(a0.w, a1.w, a2.w, a3.w, b0.w, b1.w, b2.w, b3.w,
                 o0.w, o1.w, o2.w, o3.w, o4.w, o5.w, o6.w, o7.w);

    size_t NT = (size_t)n4;
    out[t]          = o0;   // iso0
    out[t + NT]     = o1;   // iso1
    out[t + 2 * NT] = o2;   // iso2
    out[t + 3 * NT] = o3;   // iso3
    size_t ob = 4 * NT + b2d;        // y_2d region, same (BN, 4*C) layout
    out[ob]          = o4;
    out[ob + C4]     = o5;
    out[ob + 2 * C4] = o6;
    out[ob + 3 * C4] = o7;
}

extern "C" void kernel_launch(void* const* d_in, const int* in_sizes, int n_in,
                              void* d_out, int out_size, void* d_ws, size_t ws_size,
                              hipStream_t stream) {
    (void)n_in; (void)d_ws; (void)ws_size; (void)out_size;
    const float4* xA1 = (const float4*)d_in[0];
    const float4* xA2 = (const float4*)d_in[1];
    const float4* xB1 = (const float4*)d_in[2];
    const float4* xB2 = (const float4*)d_in[3];
    const float4* x2d = (const float4*)d_in[4];
    float4* out = (float4*)d_out;

    int n  = in_sizes[0];        // B*N*C = 8,388,608
    int n4 = n / 4;              // float4 groups per stream = 2,097,152

    int block = 256;
    int grid  = (n4 + block - 1) / block;   // 8192 blocks
    d8_gelu_kernel<<<grid, block, 0, stream>>>(xA1, xA2, xB1, xB2, x2d, out, n4);
}